// Round 17
// baseline (156.747 us; speedup 1.0000x reference)
//
#include <hip/hip_runtime.h>
#include <math.h>

#define B_  2
#define L_  2048
#define D_  512
#define NH_ 8
#define HD_ 64

typedef __attribute__((ext_vector_type(8))) short short8;
typedef __attribute__((ext_vector_type(4))) float f32x4;

__device__ __forceinline__ float ex2(float x) {
#if __has_builtin(__builtin_amdgcn_exp2f)
    return __builtin_amdgcn_exp2f(x);
#else
    return exp2f(x);
#endif
}
__device__ __forceinline__ float rcp_(float x) {
#if __has_builtin(__builtin_amdgcn_rcpf)
    return __builtin_amdgcn_rcpf(x);
#else
    return 1.0f / x;
#endif
}

// exp(tanh(x)):  z=e^{2x}; tanh=1-2/(z+1); e^tanh via exp2
__device__ __forceinline__ float fast_e(float x) {
    float z  = ex2(x * 2.885390082f);        // e^{2x} = 2^{2x*log2(e)}
    float th = 1.0f - 2.0f * rcp_(z + 1.0f);
    return ex2(th * 1.4426950408889634f);
}

__device__ __forceinline__ unsigned int f2bf(float x) {
    unsigned int u = __float_as_uint(x);
    u += 0x7fffu + ((u >> 16) & 1u);         // RNE
    return u >> 16;
}
__device__ __forceinline__ unsigned int pk2(float lo, float hi) {
    return f2bf(lo) | (f2bf(hi) << 16);
}

// ---------------------------------------------------------------------------
// K1: merged prep (blocks 0..3) + wconv (blocks 4..259).  256 thr.
// ---------------------------------------------------------------------------
__global__ __launch_bounds__(256) void k_pw(const float* __restrict__ Wq,
                                            const float* __restrict__ bq,
                                            const float* __restrict__ Wk,
                                            const float* __restrict__ bk,
                                            const float* __restrict__ wsc,
                                            float* __restrict__ wqwT,
                                            float* __restrict__ wkwT,
                                            float* __restrict__ bqw,
                                            float* __restrict__ bkw,
                                            const float* __restrict__ Wv,
                                            const float* __restrict__ Wd,
                                            unsigned short* __restrict__ WvF,
                                            unsigned short* __restrict__ WdFh,
                                            unsigned short* __restrict__ WdFl) {
    if (blockIdx.x < 4) {
        __shared__ float w[HD_];
        int which = blockIdx.x >> 1;
        int half  = blockIdx.x & 1;
        const float* W  = which ? Wk : Wq;
        const float* bb = which ? bk : bq;
        float* WT = which ? wkwT : wqwT;
        float* bo = which ? bkw  : bqw;
        if (threadIdx.x < HD_) w[threadIdx.x] = wsc[which * HD_ + threadIdx.x];
        __syncthreads();
        int r = half * 256 + threadIdx.x;
        for (int h = 0; h < NH_; ++h) {
            float s = 0.f;
            #pragma unroll 8
            for (int d = 0; d < HD_; ++d) s += W[r * D_ + h * HD_ + d] * w[d];
            WT[h * D_ + r] = s;
        }
        if (half == 0 && threadIdx.x < NH_) {
            int h = threadIdx.x;
            float s = 0.f;
            for (int d = 0; d < HD_; ++d) s += bb[h * HD_ + d] * w[d];
            bo[h] = s;
        }
    } else {
        int id = (blockIdx.x - 4) * 256 + threadIdx.x;   // 0..65535
        int wy = id >> 15;                               // 0: Wv, 1: Wd
        int wid = id & 32767;
        int lane = wid & 63;
        int kb = (wid >> 6) & 15;
        int nf = wid >> 10;                              // 0..31
        int l15 = lane & 15, lg = lane >> 4;
        int n = nf * 16 + l15;
        int k0 = kb * 32 + lg * 4;
        size_t base = ((size_t)(nf * 16 + kb) * 64 + lane) * 8;
        if (wy == 0) {
            #pragma unroll
            for (int j = 0; j < 8; ++j) {
                int k = k0 + (j & 3) + 16 * (j >> 2);
                WvF[base + j] = (unsigned short)f2bf(Wv[(size_t)k * 512 + n]);
            }
        } else {
            #pragma unroll
            for (int j = 0; j < 8; ++j) {
                int k = k0 + (j & 3) + 16 * (j >> 2);
                float x = Wd[(size_t)k * 512 + n];
                unsigned int h = f2bf(x);
                float hf = __uint_as_float(h << 16);
                WdFh[base + j] = (unsigned short)h;
                WdFl[base + j] = (unsigned short)f2bf(x - hf);
            }
        }
    }
}

// ---------------------------------------------------------------------------
// K2: merged mmA (bx%5==0) + qwkw (else).  2560 blocks x 256 thr.  (r13 body)
// ---------------------------------------------------------------------------
__global__ __launch_bounds__(256) void k_qm(const float* __restrict__ q,
                                            const float* __restrict__ k,
                                            const float* __restrict__ wqwT,
                                            const float* __restrict__ wkwT,
                                            const float* __restrict__ bqw,
                                            const float* __restrict__ bkw,
                                            float* __restrict__ qw,
                                            float* __restrict__ kw,
                                            const float* __restrict__ A,
                                            const short8* __restrict__ BF,
                                            const float* __restrict__ bias,
                                            unsigned short* __restrict__ vxg) {
    int bx = blockIdx.x;
    int tid = threadIdx.x;
    if (bx % 5 == 0) {
        // ------------------------- mmA -------------------------------------
        int mb = bx / 5;                 // 0..511
        int m0 = (mb & 63) * 64;
        int n0q = (mb >> 6) * 4;
        int w = tid >> 6, lane = tid & 63;
        int l15 = lane & 15, lg = lane >> 4;
        f32x4 acc[4];
        #pragma unroll
        for (int j = 0; j < 4; ++j) acc[j] = (f32x4){0.f, 0.f, 0.f, 0.f};

        const float* a0 = A + (size_t)(m0 + w * 16 + l15) * 512 + lg * 4;

        float4 clo = *(const float4*)(a0);
        float4 chi = *(const float4*)(a0 + 16);
        short8 cb[4];
        #pragma unroll
        for (int nf = 0; nf < 4; ++nf) cb[nf] = BF[(size_t)(n0q + nf) * 16 * 64 + lane];

        for (int kb = 0; kb < 16; ++kb) {
            float4 lo = clo, hi = chi;
            short8 b0 = cb[0], b1 = cb[1], b2 = cb[2], b3 = cb[3];
            if (kb < 15) {
                clo = *(const float4*)(a0 + (kb + 1) * 32);
                chi = *(const float4*)(a0 + (kb + 1) * 32 + 16);
                #pragma unroll
                for (int nf = 0; nf < 4; ++nf)
                    cb[nf] = BF[((size_t)(n0q + nf) * 16 + kb + 1) * 64 + lane];
            }
            union { unsigned int u[4]; short8 s; } af;
            asm("v_cvt_pk_bf16_f32 %0, %1, %2" : "=v"(af.u[0]) : "v"(lo.x), "v"(lo.y));
            asm("v_cvt_pk_bf16_f32 %0, %1, %2" : "=v"(af.u[1]) : "v"(lo.z), "v"(lo.w));
            asm("v_cvt_pk_bf16_f32 %0, %1, %2" : "=v"(af.u[2]) : "v"(hi.x), "v"(hi.y));
            asm("v_cvt_pk_bf16_f32 %0, %1, %2" : "=v"(af.u[3]) : "v"(hi.z), "v"(hi.w));
            acc[0] = __builtin_amdgcn_mfma_f32_16x16x32_bf16(af.s, b0, acc[0], 0, 0, 0);
            acc[1] = __builtin_amdgcn_mfma_f32_16x16x32_bf16(af.s, b1, acc[1], 0, 0, 0);
            acc[2] = __builtin_amdgcn_mfma_f32_16x16x32_bf16(af.s, b2, acc[2], 0, 0, 0);
            acc[3] = __builtin_amdgcn_mfma_f32_16x16x32_bf16(af.s, b3, acc[3], 0, 0, 0);
        }
        int m = m0 + w * 16 + lg * 4;
        int b = m >> 11, kk = m & 2047;
        int kblk = kk >> 5, base32 = kk & 31;
        int ie0 = 4 * (base32 >> 4);
        int lvsel = 16 * ((base32 >> 2) & 3);
        #pragma unroll
        for (int nf = 0; nf < 4; ++nf) {
            int n = (n0q + nf) * 16 + l15;
            float bvv = bias[n];
            int h = n >> 6, dt = (n >> 4) & 3, ncol = n & 15;
            int lane_v = ncol + lvsel;
            size_t ad = ((((size_t)((h * 2 + b) * 64 + kblk)) * 4 + dt) * 64 + lane_v) * 8 + ie0;
            uint2 pkt;
            pkt.x = pk2(acc[nf][0] + bvv, acc[nf][1] + bvv);
            pkt.y = pk2(acc[nf][2] + bvv, acc[nf][3] + bvv);
            *(uint2*)(vxg + ad) = pkt;
        }
    } else {
        // ------------------------- qwkw ------------------------------------
        int qb = bx - bx / 5 - 1;        // 0..2047
        int wid  = qb * 4 + (tid >> 6);
        int lane = tid & 63;
        int sel  = wid >= 4096;
        int row  = wid & 4095;
        const float* src = sel ? k : q;
        const float* WT  = sel ? wkwT : wqwT;
        const float* bo  = sel ? bkw : bqw;
        float* dst = sel ? kw : qw;
        float4 va = *(const float4*)(src + (size_t)row * D_ + lane * 4);
        float4 vb = *(const float4*)(src + (size_t)row * D_ + 256 + lane * 4);
        float res[NH_];
        #pragma unroll
        for (int h = 0; h < NH_; ++h) {
            float4 wa = *(const float4*)(WT + h * D_ + lane * 4);
            float4 wb = *(const float4*)(WT + h * D_ + 256 + lane * 4);
            float s = va.x*wa.x + va.y*wa.y + va.z*wa.z + va.w*wa.w
                    + vb.x*wb.x + vb.y*wb.y + vb.z*wb.z + vb.w*wb.w;
            #pragma unroll
            for (int off = 32; off; off >>= 1) s += __shfl_xor(s, off);
            res[h] = s + bo[h];
        }
        if (lane == 0) {
            #pragma unroll
            for (int h = 0; h < NH_; ++h) dst[h * 4096 + row] = res[h];
        }
    }
}

// ---------------------------------------------------------------------------
// K4: main fused kernel, MFMA PV, k-split.  e via 2048-entry LDS pair-table
// + linear interp (r16-proven).  Row-sums via 5th MFMA vs all-ones B.
// ---------------------------------------------------------------------------
__global__ __launch_bounds__(512, 4) void k_main(const float* __restrict__ qw,
                                                 const float* __restrict__ kw,
                                                 const short8* __restrict__ vgs,
                                                 float* __restrict__ att,
                                                 float* __restrict__ rsum_o) {
    int hb  = blockIdx.y;
    int q0  = blockIdx.x * 64;
    int tid = threadIdx.x;
    int w   = tid >> 6;
    int wq  = w & 3;
    int kh  = w >> 2;
    int lane = tid & 63;
    int l15 = lane & 15, lg = lane >> 4;

    __shared__ float kws[2048];                 // 8 KB
    __shared__ float red[4][16][68];            // 17.4 KB half-combine buffer
    __shared__ float2 tbl[2048];                // 16 KB interp pair-table

    *(float4*)&kws[tid * 4] = *(const float4*)(kw + hb * 2048 + tid * 4);
    #pragma unroll
    for (int ii = 0; ii < 4; ++ii) {
        int idx = tid + ii * 512;
        float x0 = -8.f + idx * 0.0078125f;
        float2 pr;
        pr.x = fast_e(x0);
        pr.y = fast_e(x0 + 0.0078125f);
        tbl[idx] = pr;
    }
    __syncthreads();

    float qwv = qw[hb * 2048 + q0 + wq * 16 + l15];
    const short8* bp = vgs + (size_t)hb * 16384 + lane;

    f32x4 acc0 = {0,0,0,0}, acc1 = {0,0,0,0}, acc2 = {0,0,0,0}, acc3 = {0,0,0,0};
    f32x4 accs = {0,0,0,0};
    union { unsigned int u[4]; short8 s; } ones_;
    ones_.u[0] = 0x3f803f80u; ones_.u[1] = 0x3f803f80u;
    ones_.u[2] = 0x3f803f80u; ones_.u[3] = 0x3f803f80u;

    int kb0 = kh * 32;
    const short8* pb = bp + (size_t)kb0 * 256;
    short8 cb0 = pb[0], cb1 = pb[64], cb2 = pb[128], cb3 = pb[192];
    float4 ckw0 = *(const float4*)&kws[kb0 * 32 + lg * 4];
    float4 ckw1 = *(const float4*)&kws[kb0 * 32 + lg * 4 + 16];

    #define EV_(XV, DST) { \
        float t_ = fminf(fmaxf(__builtin_fmaf((XV), 128.f, 1024.f), 0.f), 2047.f); \
        float fi_ = floorf(t_); \
        float2 p_ = tbl[(int)fi_]; \
        DST = __builtin_fmaf(t_ - fi_, p_.y - p_.x, p_.x); }

    for (int i = 0; i < 32; ++i) {
        short8 b0 = cb0, b1 = cb1, b2 = cb2, b3 = cb3;
        float4 kw0 = ckw0, kw1 = ckw1;
        if (i < 31) {                           // depth-1 prefetch
            const short8* nb = bp + (size_t)(kb0 + i + 1) * 256;
            cb0 = nb[0]; cb1 = nb[64]; cb2 = nb[128]; cb3 = nb[192];
            int nk = (kb0 + i + 1) * 32 + lg * 4;
            ckw0 = *(const float4*)&kws[nk];
            ckw1 = *(const float4*)&kws[nk + 16];
        }
        float e0, e1, e2, e3, e4, e5, e6, e7;
        EV_(qwv + kw0.x, e0) EV_(qwv + kw0.y, e1)
        EV_(qwv + kw0.z, e2) EV_(qwv + kw0.w, e3)
        EV_(qwv + kw1.x, e4) EV_(qwv + kw1.y, e5)
        EV_(qwv + kw1.z, e6) EV_(qwv + kw1.w, e7)
        union { unsigned int u[4]; short8 s; } af;
        asm("v_cvt_pk_bf16_f32 %0, %1, %2" : "=v"(af.u[0]) : "v"(e0), "v"(e1));
        asm("v_cvt_pk_bf16_f32 %0, %1, %2" : "=v"(af.u[1]) : "v"(e2), "v"(e3));
        asm("v_cvt_pk_bf16_f32 %0, %1, %2" : "=v"(af.u[2]) : "v"(e4), "v"(e5));
        asm("v_cvt_pk_bf16_f32 %0, %1, %2" : "=v"(af.u[3]) : "v"(e6), "v"(e7));
        acc0 = __builtin_amdgcn_mfma_f32_16x16x32_bf16(af.s, b0, acc0, 0, 0, 0);
        acc1 = __builtin_amdgcn_mfma_f32_16x16x32_bf16(af.s, b1, acc1, 0, 0, 0);
        acc2 = __builtin_amdgcn_mfma_f32_16x16x32_bf16(af.s, b2, acc2, 0, 0, 0);
        acc3 = __builtin_amdgcn_mfma_f32_16x16x32_bf16(af.s, b3, acc3, 0, 0, 0);
        accs = __builtin_amdgcn_mfma_f32_16x16x32_bf16(af.s, ones_.s, accs, 0, 0, 0);
    }
    #undef EV_

    if (kh == 1) {
        #define WR_(dt, accv) \
            red[wq][lg * 4 + 0][dt * 16 + l15] = accv[0]; \
            red[wq][lg * 4 + 1][dt * 16 + l15] = accv[1]; \
            red[wq][lg * 4 + 2][dt * 16 + l15] = accv[2]; \
            red[wq][lg * 4 + 3][dt * 16 + l15] = accv[3];
        WR_(0, acc0) WR_(1, acc1) WR_(2, acc2) WR_(3, acc3)
        #undef WR_
        if (l15 == 0) {
            red[wq][lg * 4 + 0][64] = accs[0];
            red[wq][lg * 4 + 1][64] = accs[1];
            red[wq][lg * 4 + 2][64] = accs[2];
            red[wq][lg * 4 + 3][64] = accs[3];
        }
    }
    __syncthreads();
    if (kh == 0) {
        #define RD_(dt, accv) \
            accv[0] += red[wq][lg * 4 + 0][dt * 16 + l15]; \
            accv[1] += red[wq][lg * 4 + 1][dt * 16 + l15]; \
            accv[2] += red[wq][lg * 4 + 2][dt * 16 + l15]; \
            accv[3] += red[wq][lg * 4 + 3][dt * 16 + l15];
        RD_(0, acc0) RD_(1, acc1) RD_(2, acc2) RD_(3, acc3)
        #undef RD_
        float rs0 = 1.0f / (accs[0] + red[wq][lg * 4 + 0][64]);
        float rs1 = 1.0f / (accs[1] + red[wq][lg * 4 + 1][64]);
        float rs2 = 1.0f / (accs[2] + red[wq][lg * 4 + 2][64]);
        float rs3 = 1.0f / (accs[3] + red[wq][lg * 4 + 3][64]);
        if (l15 == 0) {
            rsum_o[hb * 2048 + q0 + wq * 16 + lg * 4 + 0] = rs0;
            rsum_o[hb * 2048 + q0 + wq * 16 + lg * 4 + 1] = rs1;
            rsum_o[hb * 2048 + q0 + wq * 16 + lg * 4 + 2] = rs2;
            rsum_o[hb * 2048 + q0 + wq * 16 + lg * 4 + 3] = rs3;
        }
        int b_ = hb & 1, h = hb >> 1;
        float* ab = att + ((size_t)(b_ * 2048 + q0 + wq * 16 + lg * 4)) * 512 + h * 64 + l15;
        #define ST_(dt, accv) \
            ab[0 * 512 + dt * 16] = accv[0] * rs0; \
            ab[1 * 512 + dt * 16] = accv[1] * rs1; \
            ab[2 * 512 + dt * 16] = accv[2] * rs2; \
            ab[3 * 512 + dt * 16] = accv[3] * rs3;
        ST_(0, acc0) ST_(1, acc1) ST_(2, acc2) ST_(3, acc3)
        #undef ST_
    }
}

// ---------------------------------------------------------------------------
// K5: merged score (4 of 5 blocks, 16 rows/block) + mmB (bx%5==0).
// Score now uses the pair-table + interp instead of 3-trans fast_e
// (cuts ~14 us of quarter-rate transcendental issue).  mmB unchanged.
// ---------------------------------------------------------------------------
__global__ __launch_bounds__(256) void k_sm(const float* __restrict__ qw,
                                            const float* __restrict__ kw,
                                            const float* __restrict__ rsum,
                                            float* __restrict__ score,
                                            const float* __restrict__ A,
                                            const short8* __restrict__ BFh,
                                            const short8* __restrict__ BFl,
                                            const float* __restrict__ bias,
                                            float* __restrict__ C) {
    __shared__ float kws[2048];
    __shared__ float2 tbl[2048];                 // used by score blocks only
    int bx  = blockIdx.x;
    int tid = threadIdx.x;
    if (bx % 5 == 0) {
        // ------------------------- mmB -------------------------------------
        int mb = bx / 5;                 // 0..511
        int m0 = (mb & 63) * 64;
        int n0q = (mb >> 6) * 4;
        int w = tid >> 6, lane = tid & 63;
        int l15 = lane & 15, lg = lane >> 4;
        f32x4 acc[4];
        #pragma unroll
        for (int j = 0; j < 4; ++j) acc[j] = (f32x4){0.f, 0.f, 0.f, 0.f};

        const float* a0 = A + (size_t)(m0 + w * 16 + l15) * 512 + lg * 4;

        float4 clo = *(const float4*)(a0);
        float4 chi = *(const float4*)(a0 + 16);

        for (int kb = 0; kb < 16; ++kb) {
            float4 lo = clo, hi = chi;
            if (kb < 15) {
                clo = *(const float4*)(a0 + (kb + 1) * 32);
                chi = *(const float4*)(a0 + (kb + 1) * 32 + 16);
            }
            union { unsigned int u[4]; short8 s; } ah, al;
            {
                float xs[8] = {lo.x, lo.y, lo.z, lo.w, hi.x, hi.y, hi.z, hi.w};
                unsigned int hu[8]; float lf[8];
                #pragma unroll
                for (int j = 0; j < 8; ++j) {
                    hu[j] = f2bf(xs[j]);
                    lf[j] = xs[j] - __uint_as_float(hu[j] << 16);
                }
                #pragma unroll
                for (int j = 0; j < 4; ++j) {
                    ah.u[j] = hu[2 * j] | (hu[2 * j + 1] << 16);
                    al.u[j] = pk2(lf[2 * j], lf[2 * j + 1]);
                }
            }
            #pragma unroll
            for (int nf = 0; nf < 4; ++nf) {
                size_t bi = ((size_t)(n0q + nf) * 16 + kb) * 64 + lane;
                short8 bh = BFh[bi];
                short8 bl = BFl[bi];
                acc[nf] = __builtin_amdgcn_mfma_f32_16x16x32_bf16(ah.s, bh, acc[nf], 0, 0, 0);
                acc[nf] = __builtin_amdgcn_mfma_f32_16x16x32_bf16(al.s, bh, acc[nf], 0, 0, 0);
                acc[nf] = __builtin_amdgcn_mfma_f32_16x16x32_bf16(ah.s, bl, acc[nf], 0, 0, 0);
            }
        }
        #pragma unroll
        for (int nf = 0; nf < 4; ++nf) {
            int n = (n0q + nf) * 16 + l15;
            float bdv = bias[n];
            #pragma unroll
            for (int r = 0; r < 4; ++r) {
                int m = m0 + w * 16 + lg * 4 + r;
                C[(size_t)m * 512 + n] = acc[nf][r] + bdv;
            }
        }
    } else {
        // ------------------------- score (16 rows/block, table-e) ----------
        int sb = bx - bx / 5 - 1;        // 0..2047
        int hb = sb >> 7;                // 16
        int qx = sb & 127;               // 128 q-blocks of 16 rows
        *(float4*)&kws[tid * 8]     = *(const float4*)(kw + hb * 2048 + tid * 8);
        *(float4*)&kws[tid * 8 + 4] = *(const float4*)(kw + hb * 2048 + tid * 8 + 4);
        #pragma unroll
        for (int ii = 0; ii < 8; ++ii) {
            int idx = tid + ii * 256;
            float x0 = -8.f + idx * 0.0078125f;
            float2 pr;
            pr.x = fast_e(x0);
            pr.y = fast_e(x0 + 0.0078125f);
            tbl[idx] = pr;
        }
        __syncthreads();
        int rl  = tid >> 4;              // 0..15 (row)
        int t16 = tid & 15;
        int qrow = qx * 16 + rl;
        float qwv = qw[hb * 2048 + qrow];
        float rs  = rsum[hb * 2048 + qrow];
        float* outp = score + ((size_t)(hb * 2048 + qrow)) * 2048;
        #define EVS_(XV, DST) { \
            float t_ = fminf(fmaxf(__builtin_fmaf((XV), 128.f, 1024.f), 0.f), 2047.f); \
            float fi_ = floorf(t_); \
            float2 p_ = tbl[(int)fi_]; \
            DST = __builtin_fmaf(t_ - fi_, p_.y - p_.x, p_.x) * rs; }
        #pragma unroll
        for (int i = 0; i < 32; ++i) {
            int kk = i * 64 + t16 * 4;
            float4 o;
            EVS_(qwv + kws[kk + 0], o.x)
            EVS_(qwv + kws[kk + 1], o.y)
            EVS_(qwv + kws[kk + 2], o.z)
            EVS_(qwv + kws[kk + 3], o.w)
            *(float4*)(outp + kk) = o;
        }
        #undef EVS_
    }
}

// ---------------------------------------------------------------------------
extern "C" void kernel_launch(void* const* d_in, const int* in_sizes, int n_in,
                              void* d_out, int out_size, void* d_ws, size_t ws_size,
                              hipStream_t stream) {
    (void)in_sizes; (void)n_in; (void)out_size; (void)ws_size;
    const float* q   = (const float*)d_in[0];
    const float* k   = (const float*)d_in[1];
    const float* v   = (const float*)d_in[2];
    const float* Wq  = (const float*)d_in[3];
    const float* bq  = (const float*)d_in[4];
    const float* Wk  = (const float*)d_in[5];
    const float* bk  = (const float*)d_in[6];
    const float* Wv  = (const float*)d_in[7];
    const float* bv  = (const float*)d_in[8];
    const float* wsc = (const float*)d_in[9];
    const float* Wd  = (const float*)d_in[10];
    const float* bd  = (const float*)d_in[11];

    float* out   = (float*)d_out;                       // (2,2048,512)
    float* score = out + (size_t)B_ * L_ * D_;          // (16,2048,2048)

    float* ws    = (float*)d_ws;
    float* wqwT  = ws;                 // 4096
    float* wkwT  = ws + 4096;          // 4096
    float* bqw   = ws + 8192;          // 8 (padded)
    float* bkw   = ws + 8256;          // 8 (padded)
    float* qw    = ws + 8704;          // 32768
    float* kw    = ws + 41472;         // 32768
    float* rsum  = ws + 74240;         // 32768
    float* vxg   = ws + 107008;        // 2,097,152 bf16 = 1,048,576 f32 slots
    float* att   = ws + 1155584;       // 2,097,152 f32
    float* WvF   = ws + 3252736;       // 262,144 bf16 = 131,072 f32 slots
    float* WdFh  = ws + 3383808;       // 131,072 f32 slots
    float* WdFl  = ws + 3514880;       // 131,072 f32 slots

    k_pw<<<dim3(260), dim3(256), 0, stream>>>(Wq, bq, Wk, bk, wsc,
        wqwT, wkwT, bqw, bkw, Wv, Wd,
        (unsigned short*)WvF, (unsigned short*)WdFh, (unsigned short*)WdFl);
    k_qm<<<dim3(2560), dim3(256), 0, stream>>>(q, k, wqwT, wkwT, bqw, bkw,
        qw, kw, v, (const short8*)WvF, bv, (unsigned short*)vxg);
    k_main<<<dim3(32, 16), dim3(512), 0, stream>>>(qw, kw, (const short8*)vxg,
        att, rsum);
    k_sm<<<dim3(2560), dim3(256), 0, stream>>>(qw, kw, rsum, score,
        att, (const short8*)WdFh, (const short8*)WdFl, bd, out);
}

// Round 18
// 150.744 us; speedup vs baseline: 1.0398x; 1.0398x over previous
//
#include <hip/hip_runtime.h>
#include <math.h>

#define B_  2
#define L_  2048
#define D_  512
#define NH_ 8
#define HD_ 64

typedef __attribute__((ext_vector_type(8))) short short8;
typedef __attribute__((ext_vector_type(4))) float f32x4;

__device__ __forceinline__ float ex2(float x) {
#if __has_builtin(__builtin_amdgcn_exp2f)
    return __builtin_amdgcn_exp2f(x);
#else
    return exp2f(x);
#endif
}
__device__ __forceinline__ float rcp_(float x) {
#if __has_builtin(__builtin_amdgcn_rcpf)
    return __builtin_amdgcn_rcpf(x);
#else
    return 1.0f / x;
#endif
}

// exp(tanh(x)):  z=e^{2x}; tanh=1-2/(z+1); e^tanh via exp2
__device__ __forceinline__ float fast_e(float x) {
    float z  = ex2(x * 2.885390082f);        // e^{2x} = 2^{2x*log2(e)}
    float th = 1.0f - 2.0f * rcp_(z + 1.0f);
    return ex2(th * 1.4426950408889634f);
}

__device__ __forceinline__ unsigned int f2bf(float x) {
    unsigned int u = __float_as_uint(x);
    u += 0x7fffu + ((u >> 16) & 1u);         // RNE
    return u >> 16;
}
__device__ __forceinline__ unsigned int pk2(float lo, float hi) {
    return f2bf(lo) | (f2bf(hi) << 16);
}

// ---------------------------------------------------------------------------
// K1: merged prep (blocks 0..3) + wconv (blocks 4..259).  256 thr.
// ---------------------------------------------------------------------------
__global__ __launch_bounds__(256) void k_pw(const float* __restrict__ Wq,
                                            const float* __restrict__ bq,
                                            const float* __restrict__ Wk,
                                            const float* __restrict__ bk,
                                            const float* __restrict__ wsc,
                                            float* __restrict__ wqwT,
                                            float* __restrict__ wkwT,
                                            float* __restrict__ bqw,
                                            float* __restrict__ bkw,
                                            const float* __restrict__ Wv,
                                            const float* __restrict__ Wd,
                                            unsigned short* __restrict__ WvF,
                                            unsigned short* __restrict__ WdFh,
                                            unsigned short* __restrict__ WdFl) {
    if (blockIdx.x < 4) {
        __shared__ float w[HD_];
        int which = blockIdx.x >> 1;
        int half  = blockIdx.x & 1;
        const float* W  = which ? Wk : Wq;
        const float* bb = which ? bk : bq;
        float* WT = which ? wkwT : wqwT;
        float* bo = which ? bkw  : bqw;
        if (threadIdx.x < HD_) w[threadIdx.x] = wsc[which * HD_ + threadIdx.x];
        __syncthreads();
        int r = half * 256 + threadIdx.x;
        for (int h = 0; h < NH_; ++h) {
            float s = 0.f;
            #pragma unroll 8
            for (int d = 0; d < HD_; ++d) s += W[r * D_ + h * HD_ + d] * w[d];
            WT[h * D_ + r] = s;
        }
        if (half == 0 && threadIdx.x < NH_) {
            int h = threadIdx.x;
            float s = 0.f;
            for (int d = 0; d < HD_; ++d) s += bb[h * HD_ + d] * w[d];
            bo[h] = s;
        }
    } else {
        int id = (blockIdx.x - 4) * 256 + threadIdx.x;   // 0..65535
        int wy = id >> 15;                               // 0: Wv, 1: Wd
        int wid = id & 32767;
        int lane = wid & 63;
        int kb = (wid >> 6) & 15;
        int nf = wid >> 10;                              // 0..31
        int l15 = lane & 15, lg = lane >> 4;
        int n = nf * 16 + l15;
        int k0 = kb * 32 + lg * 4;
        size_t base = ((size_t)(nf * 16 + kb) * 64 + lane) * 8;
        if (wy == 0) {
            #pragma unroll
            for (int j = 0; j < 8; ++j) {
                int k = k0 + (j & 3) + 16 * (j >> 2);
                WvF[base + j] = (unsigned short)f2bf(Wv[(size_t)k * 512 + n]);
            }
        } else {
            #pragma unroll
            for (int j = 0; j < 8; ++j) {
                int k = k0 + (j & 3) + 16 * (j >> 2);
                float x = Wd[(size_t)k * 512 + n];
                unsigned int h = f2bf(x);
                float hf = __uint_as_float(h << 16);
                WdFh[base + j] = (unsigned short)h;
                WdFl[base + j] = (unsigned short)f2bf(x - hf);
            }
        }
    }
}

// ---------------------------------------------------------------------------
// K2: merged mmA (bx%5==0) + qwkw (else).  2560 blocks x 256 thr.  (r13 body)
// ---------------------------------------------------------------------------
__global__ __launch_bounds__(256) void k_qm(const float* __restrict__ q,
                                            const float* __restrict__ k,
                                            const float* __restrict__ wqwT,
                                            const float* __restrict__ wkwT,
                                            const float* __restrict__ bqw,
                                            const float* __restrict__ bkw,
                                            float* __restrict__ qw,
                                            float* __restrict__ kw,
                                            const float* __restrict__ A,
                                            const short8* __restrict__ BF,
                                            const float* __restrict__ bias,
                                            unsigned short* __restrict__ vxg) {
    int bx = blockIdx.x;
    int tid = threadIdx.x;
    if (bx % 5 == 0) {
        // ------------------------- mmA -------------------------------------
        int mb = bx / 5;                 // 0..511
        int m0 = (mb & 63) * 64;
        int n0q = (mb >> 6) * 4;
        int w = tid >> 6, lane = tid & 63;
        int l15 = lane & 15, lg = lane >> 4;
        f32x4 acc[4];
        #pragma unroll
        for (int j = 0; j < 4; ++j) acc[j] = (f32x4){0.f, 0.f, 0.f, 0.f};

        const float* a0 = A + (size_t)(m0 + w * 16 + l15) * 512 + lg * 4;

        float4 clo = *(const float4*)(a0);
        float4 chi = *(const float4*)(a0 + 16);
        short8 cb[4];
        #pragma unroll
        for (int nf = 0; nf < 4; ++nf) cb[nf] = BF[(size_t)(n0q + nf) * 16 * 64 + lane];

        for (int kb = 0; kb < 16; ++kb) {
            float4 lo = clo, hi = chi;
            short8 b0 = cb[0], b1 = cb[1], b2 = cb[2], b3 = cb[3];
            if (kb < 15) {
                clo = *(const float4*)(a0 + (kb + 1) * 32);
                chi = *(const float4*)(a0 + (kb + 1) * 32 + 16);
                #pragma unroll
                for (int nf = 0; nf < 4; ++nf)
                    cb[nf] = BF[((size_t)(n0q + nf) * 16 + kb + 1) * 64 + lane];
            }
            union { unsigned int u[4]; short8 s; } af;
            asm("v_cvt_pk_bf16_f32 %0, %1, %2" : "=v"(af.u[0]) : "v"(lo.x), "v"(lo.y));
            asm("v_cvt_pk_bf16_f32 %0, %1, %2" : "=v"(af.u[1]) : "v"(lo.z), "v"(lo.w));
            asm("v_cvt_pk_bf16_f32 %0, %1, %2" : "=v"(af.u[2]) : "v"(hi.x), "v"(hi.y));
            asm("v_cvt_pk_bf16_f32 %0, %1, %2" : "=v"(af.u[3]) : "v"(hi.z), "v"(hi.w));
            acc[0] = __builtin_amdgcn_mfma_f32_16x16x32_bf16(af.s, b0, acc[0], 0, 0, 0);
            acc[1] = __builtin_amdgcn_mfma_f32_16x16x32_bf16(af.s, b1, acc[1], 0, 0, 0);
            acc[2] = __builtin_amdgcn_mfma_f32_16x16x32_bf16(af.s, b2, acc[2], 0, 0, 0);
            acc[3] = __builtin_amdgcn_mfma_f32_16x16x32_bf16(af.s, b3, acc[3], 0, 0, 0);
        }
        int m = m0 + w * 16 + lg * 4;
        int b = m >> 11, kk = m & 2047;
        int kblk = kk >> 5, base32 = kk & 31;
        int ie0 = 4 * (base32 >> 4);
        int lvsel = 16 * ((base32 >> 2) & 3);
        #pragma unroll
        for (int nf = 0; nf < 4; ++nf) {
            int n = (n0q + nf) * 16 + l15;
            float bvv = bias[n];
            int h = n >> 6, dt = (n >> 4) & 3, ncol = n & 15;
            int lane_v = ncol + lvsel;
            size_t ad = ((((size_t)((h * 2 + b) * 64 + kblk)) * 4 + dt) * 64 + lane_v) * 8 + ie0;
            uint2 pkt;
            pkt.x = pk2(acc[nf][0] + bvv, acc[nf][1] + bvv);
            pkt.y = pk2(acc[nf][2] + bvv, acc[nf][3] + bvv);
            *(uint2*)(vxg + ad) = pkt;
        }
    } else {
        // ------------------------- qwkw ------------------------------------
        int qb = bx - bx / 5 - 1;        // 0..2047
        int wid  = qb * 4 + (tid >> 6);
        int lane = tid & 63;
        int sel  = wid >= 4096;
        int row  = wid & 4095;
        const float* src = sel ? k : q;
        const float* WT  = sel ? wkwT : wqwT;
        const float* bo  = sel ? bkw : bqw;
        float* dst = sel ? kw : qw;
        float4 va = *(const float4*)(src + (size_t)row * D_ + lane * 4);
        float4 vb = *(const float4*)(src + (size_t)row * D_ + 256 + lane * 4);
        float res[NH_];
        #pragma unroll
        for (int h = 0; h < NH_; ++h) {
            float4 wa = *(const float4*)(WT + h * D_ + lane * 4);
            float4 wb = *(const float4*)(WT + h * D_ + 256 + lane * 4);
            float s = va.x*wa.x + va.y*wa.y + va.z*wa.z + va.w*wa.w
                    + vb.x*wb.x + vb.y*wb.y + vb.z*wb.z + vb.w*wb.w;
            #pragma unroll
            for (int off = 32; off; off >>= 1) s += __shfl_xor(s, off);
            res[h] = s + bo[h];
        }
        if (lane == 0) {
            #pragma unroll
            for (int h = 0; h < NH_; ++h) dst[h * 4096 + row] = res[h];
        }
    }
}

// ---------------------------------------------------------------------------
// K4: main fused kernel, MFMA PV, k-split.  e = exp(tanh(x)) via 2048-entry
// LDS pair-table + linear interp (x clamped to [-8,8], spacing 1/128).
// Row-sums via 5th MFMA vs all-ones B; A-pack via v_cvt_pk_bf16_f32.
// ---------------------------------------------------------------------------
__global__ __launch_bounds__(512, 4) void k_main(const float* __restrict__ qw,
                                                 const float* __restrict__ kw,
                                                 const short8* __restrict__ vgs,
                                                 float* __restrict__ att,
                                                 float* __restrict__ rsum_o) {
    int hb  = blockIdx.y;
    int q0  = blockIdx.x * 64;
    int tid = threadIdx.x;
    int w   = tid >> 6;
    int wq  = w & 3;
    int kh  = w >> 2;
    int lane = tid & 63;
    int l15 = lane & 15, lg = lane >> 4;

    __shared__ float kws[2048];                 // 8 KB
    __shared__ float red[4][16][68];            // 17.4 KB half-combine buffer
    __shared__ float2 tbl[2048];                // 16 KB interp pair-table

    *(float4*)&kws[tid * 4] = *(const float4*)(kw + hb * 2048 + tid * 4);
    #pragma unroll
    for (int ii = 0; ii < 4; ++ii) {
        int idx = tid + ii * 512;
        float x0 = -8.f + idx * 0.0078125f;
        float2 pr;
        pr.x = fast_e(x0);
        pr.y = fast_e(x0 + 0.0078125f);
        tbl[idx] = pr;
    }
    __syncthreads();

    float qwv = qw[hb * 2048 + q0 + wq * 16 + l15];
    const short8* bp = vgs + (size_t)hb * 16384 + lane;

    f32x4 acc0 = {0,0,0,0}, acc1 = {0,0,0,0}, acc2 = {0,0,0,0}, acc3 = {0,0,0,0};
    f32x4 accs = {0,0,0,0};
    union { unsigned int u[4]; short8 s; } ones_;
    ones_.u[0] = 0x3f803f80u; ones_.u[1] = 0x3f803f80u;
    ones_.u[2] = 0x3f803f80u; ones_.u[3] = 0x3f803f80u;

    int kb0 = kh * 32;
    const short8* pb = bp + (size_t)kb0 * 256;
    short8 cb0 = pb[0], cb1 = pb[64], cb2 = pb[128], cb3 = pb[192];
    float4 ckw0 = *(const float4*)&kws[kb0 * 32 + lg * 4];
    float4 ckw1 = *(const float4*)&kws[kb0 * 32 + lg * 4 + 16];

    #define EV_(XV, DST) { \
        float t_ = fminf(fmaxf(__builtin_fmaf((XV), 128.f, 1024.f), 0.f), 2047.f); \
        float fi_ = floorf(t_); \
        float2 p_ = tbl[(int)fi_]; \
        DST = __builtin_fmaf(t_ - fi_, p_.y - p_.x, p_.x); }

    for (int i = 0; i < 32; ++i) {
        short8 b0 = cb0, b1 = cb1, b2 = cb2, b3 = cb3;
        float4 kw0 = ckw0, kw1 = ckw1;
        if (i < 31) {                           // depth-1 prefetch
            const short8* nb = bp + (size_t)(kb0 + i + 1) * 256;
            cb0 = nb[0]; cb1 = nb[64]; cb2 = nb[128]; cb3 = nb[192];
            int nk = (kb0 + i + 1) * 32 + lg * 4;
            ckw0 = *(const float4*)&kws[nk];
            ckw1 = *(const float4*)&kws[nk + 16];
        }
        float e0, e1, e2, e3, e4, e5, e6, e7;
        EV_(qwv + kw0.x, e0) EV_(qwv + kw0.y, e1)
        EV_(qwv + kw0.z, e2) EV_(qwv + kw0.w, e3)
        EV_(qwv + kw1.x, e4) EV_(qwv + kw1.y, e5)
        EV_(qwv + kw1.z, e6) EV_(qwv + kw1.w, e7)
        union { unsigned int u[4]; short8 s; } af;
        asm("v_cvt_pk_bf16_f32 %0, %1, %2" : "=v"(af.u[0]) : "v"(e0), "v"(e1));
        asm("v_cvt_pk_bf16_f32 %0, %1, %2" : "=v"(af.u[1]) : "v"(e2), "v"(e3));
        asm("v_cvt_pk_bf16_f32 %0, %1, %2" : "=v"(af.u[2]) : "v"(e4), "v"(e5));
        asm("v_cvt_pk_bf16_f32 %0, %1, %2" : "=v"(af.u[3]) : "v"(e6), "v"(e7));
        acc0 = __builtin_amdgcn_mfma_f32_16x16x32_bf16(af.s, b0, acc0, 0, 0, 0);
        acc1 = __builtin_amdgcn_mfma_f32_16x16x32_bf16(af.s, b1, acc1, 0, 0, 0);
        acc2 = __builtin_amdgcn_mfma_f32_16x16x32_bf16(af.s, b2, acc2, 0, 0, 0);
        acc3 = __builtin_amdgcn_mfma_f32_16x16x32_bf16(af.s, b3, acc3, 0, 0, 0);
        accs = __builtin_amdgcn_mfma_f32_16x16x32_bf16(af.s, ones_.s, accs, 0, 0, 0);
    }
    #undef EV_

    if (kh == 1) {
        #define WR_(dt, accv) \
            red[wq][lg * 4 + 0][dt * 16 + l15] = accv[0]; \
            red[wq][lg * 4 + 1][dt * 16 + l15] = accv[1]; \
            red[wq][lg * 4 + 2][dt * 16 + l15] = accv[2]; \
            red[wq][lg * 4 + 3][dt * 16 + l15] = accv[3];
        WR_(0, acc0) WR_(1, acc1) WR_(2, acc2) WR_(3, acc3)
        #undef WR_
        if (l15 == 0) {
            red[wq][lg * 4 + 0][64] = accs[0];
            red[wq][lg * 4 + 1][64] = accs[1];
            red[wq][lg * 4 + 2][64] = accs[2];
            red[wq][lg * 4 + 3][64] = accs[3];
        }
    }
    __syncthreads();
    if (kh == 0) {
        #define RD_(dt, accv) \
            accv[0] += red[wq][lg * 4 + 0][dt * 16 + l15]; \
            accv[1] += red[wq][lg * 4 + 1][dt * 16 + l15]; \
            accv[2] += red[wq][lg * 4 + 2][dt * 16 + l15]; \
            accv[3] += red[wq][lg * 4 + 3][dt * 16 + l15];
        RD_(0, acc0) RD_(1, acc1) RD_(2, acc2) RD_(3, acc3)
        #undef RD_
        float rs0 = 1.0f / (accs[0] + red[wq][lg * 4 + 0][64]);
        float rs1 = 1.0f / (accs[1] + red[wq][lg * 4 + 1][64]);
        float rs2 = 1.0f / (accs[2] + red[wq][lg * 4 + 2][64]);
        float rs3 = 1.0f / (accs[3] + red[wq][lg * 4 + 3][64]);
        if (l15 == 0) {
            rsum_o[hb * 2048 + q0 + wq * 16 + lg * 4 + 0] = rs0;
            rsum_o[hb * 2048 + q0 + wq * 16 + lg * 4 + 1] = rs1;
            rsum_o[hb * 2048 + q0 + wq * 16 + lg * 4 + 2] = rs2;
            rsum_o[hb * 2048 + q0 + wq * 16 + lg * 4 + 3] = rs3;
        }
        int b_ = hb & 1, h = hb >> 1;
        float* ab = att + ((size_t)(b_ * 2048 + q0 + wq * 16 + lg * 4)) * 512 + h * 64 + l15;
        #define ST_(dt, accv) \
            ab[0 * 512 + dt * 16] = accv[0] * rs0; \
            ab[1 * 512 + dt * 16] = accv[1] * rs1; \
            ab[2 * 512 + dt * 16] = accv[2] * rs2; \
            ab[3 * 512 + dt * 16] = accv[3] * rs3;
        ST_(0, acc0) ST_(1, acc1) ST_(2, acc2) ST_(3, acc3)
        #undef ST_
    }
}

// ---------------------------------------------------------------------------
// K5: merged score (4 of 5 blocks, 16 rows/block) + mmB (bx%5==0).
// 2560 blocks x 256 thr.  (r15/r16 bodies: fast_e score, unchanged mmB)
// ---------------------------------------------------------------------------
__global__ __launch_bounds__(256) void k_sm(const float* __restrict__ qw,
                                            const float* __restrict__ kw,
                                            const float* __restrict__ rsum,
                                            float* __restrict__ score,
                                            const float* __restrict__ A,
                                            const short8* __restrict__ BFh,
                                            const short8* __restrict__ BFl,
                                            const float* __restrict__ bias,
                                            float* __restrict__ C) {
    __shared__ float kws[2048];
    int bx  = blockIdx.x;
    int tid = threadIdx.x;
    if (bx % 5 == 0) {
        // ------------------------- mmB -------------------------------------
        int mb = bx / 5;                 // 0..511
        int m0 = (mb & 63) * 64;
        int n0q = (mb >> 6) * 4;
        int w = tid >> 6, lane = tid & 63;
        int l15 = lane & 15, lg = lane >> 4;
        f32x4 acc[4];
        #pragma unroll
        for (int j = 0; j < 4; ++j) acc[j] = (f32x4){0.f, 0.f, 0.f, 0.f};

        const float* a0 = A + (size_t)(m0 + w * 16 + l15) * 512 + lg * 4;

        float4 clo = *(const float4*)(a0);
        float4 chi = *(const float4*)(a0 + 16);

        for (int kb = 0; kb < 16; ++kb) {
            float4 lo = clo, hi = chi;
            if (kb < 15) {
                clo = *(const float4*)(a0 + (kb + 1) * 32);
                chi = *(const float4*)(a0 + (kb + 1) * 32 + 16);
            }
            union { unsigned int u[4]; short8 s; } ah, al;
            {
                float xs[8] = {lo.x, lo.y, lo.z, lo.w, hi.x, hi.y, hi.z, hi.w};
                unsigned int hu[8]; float lf[8];
                #pragma unroll
                for (int j = 0; j < 8; ++j) {
                    hu[j] = f2bf(xs[j]);
                    lf[j] = xs[j] - __uint_as_float(hu[j] << 16);
                }
                #pragma unroll
                for (int j = 0; j < 4; ++j) {
                    ah.u[j] = hu[2 * j] | (hu[2 * j + 1] << 16);
                    al.u[j] = pk2(lf[2 * j], lf[2 * j + 1]);
                }
            }
            #pragma unroll
            for (int nf = 0; nf < 4; ++nf) {
                size_t bi = ((size_t)(n0q + nf) * 16 + kb) * 64 + lane;
                short8 bh = BFh[bi];
                short8 bl = BFl[bi];
                acc[nf] = __builtin_amdgcn_mfma_f32_16x16x32_bf16(ah.s, bh, acc[nf], 0, 0, 0);
                acc[nf] = __builtin_amdgcn_mfma_f32_16x16x32_bf16(al.s, bh, acc[nf], 0, 0, 0);
                acc[nf] = __builtin_amdgcn_mfma_f32_16x16x32_bf16(ah.s, bl, acc[nf], 0, 0, 0);
            }
        }
        #pragma unroll
        for (int nf = 0; nf < 4; ++nf) {
            int n = (n0q + nf) * 16 + l15;
            float bdv = bias[n];
            #pragma unroll
            for (int r = 0; r < 4; ++r) {
                int m = m0 + w * 16 + lg * 4 + r;
                C[(size_t)m * 512 + n] = acc[nf][r] + bdv;
            }
        }
    } else {
        // ------------------------- score (16 rows/block) -------------------
        int sb = bx - bx / 5 - 1;        // 0..2047
        int hb = sb >> 7;                // 16
        int qx = sb & 127;               // 128 q-blocks of 16 rows
        *(float4*)&kws[tid * 8]     = *(const float4*)(kw + hb * 2048 + tid * 8);
        *(float4*)&kws[tid * 8 + 4] = *(const float4*)(kw + hb * 2048 + tid * 8 + 4);
        __syncthreads();
        int rl  = tid >> 4;              // 0..15 (row)
        int t16 = tid & 15;
        int qrow = qx * 16 + rl;
        float qwv = qw[hb * 2048 + qrow];
        float rs  = rsum[hb * 2048 + qrow];
        float* outp = score + ((size_t)(hb * 2048 + qrow)) * 2048;
        #pragma unroll
        for (int i = 0; i < 32; ++i) {
            int kk = i * 64 + t16 * 4;
            float4 o;
            o.x = fast_e(qwv + kws[kk + 0]) * rs;
            o.y = fast_e(qwv + kws[kk + 1]) * rs;
            o.z = fast_e(qwv + kws[kk + 2]) * rs;
            o.w = fast_e(qwv + kws[kk + 3]) * rs;
            *(float4*)(outp + kk) = o;
        }
    }
}

// ---------------------------------------------------------------------------
extern "C" void kernel_launch(void* const* d_in, const int* in_sizes, int n_in,
                              void* d_out, int out_size, void* d_ws, size_t ws_size,
                              hipStream_t stream) {
    (void)in_sizes; (void)n_in; (void)out_size; (void)ws_size;
    const float* q   = (const float*)d_in[0];
    const float* k   = (const float*)d_in[1];
    const float* v   = (const float*)d_in[2];
    const float* Wq  = (const float*)d_in[3];
    const float* bq  = (const float*)d_in[4];
    const float* Wk  = (const float*)d_in[5];
    const float* bk  = (const float*)d_in[6];
    const float* Wv  = (const float*)d_in[7];
    const float* bv  = (const float*)d_in[8];
    const float* wsc = (const float*)d_in[9];
    const float* Wd  = (const float*)d_in[10];
    const float* bd  = (const float*)d_in[11];

    float* out   = (float*)d_out;                       // (2,2048,512)
    float* score = out + (size_t)B_ * L_ * D_;          // (16,2048,2048)

    float* ws    = (float*)d_ws;
    float* wqwT  = ws;                 // 4096
    float* wkwT  = ws + 4096;          // 4096
    float* bqw   = ws + 8192;          // 8 (padded)
    float* bkw   = ws + 8256;          // 8 (padded)
    float* qw    = ws + 8704;          // 32768
    float* kw    = ws + 41472;         // 32768
    float* rsum  = ws + 74240;         // 32768
    float* vxg   = ws + 107008;        // 2,097,152 bf16 = 1,048,576 f32 slots
    float* att   = ws + 1155584;       // 2,097,152 f32
    float* WvF   = ws + 3252736;       // 262,144 bf16 = 131,072 f32 slots
    float* WdFh  = ws + 3383808;       // 131,072 f32 slots
    float* WdFl  = ws + 3514880;       // 131,072 f32 slots

    k_pw<<<dim3(260), dim3(256), 0, stream>>>(Wq, bq, Wk, bk, wsc,
        wqwT, wkwT, bqw, bkw, Wv, Wd,
        (unsigned short*)WvF, (unsigned short*)WdFh, (unsigned short*)WdFl);
    k_qm<<<dim3(2560), dim3(256), 0, stream>>>(q, k, wqwT, wkwT, bqw, bkw,
        qw, kw, v, (const short8*)WvF, bv, (unsigned short*)vxg);
    k_main<<<dim3(32, 16), dim3(512), 0, stream>>>(qw, kw, (const short8*)vxg,
        att, rsum);
    k_sm<<<dim3(2560), dim3(256), 0, stream>>>(qw, kw, rsum, score,
        att, (const short8*)WdFh, (const short8*)WdFl, bd, out);
}